// Round 6
// baseline (201.756 us; speedup 1.0000x reference)
//
#include <hip/hip_runtime.h>
#include <hip/hip_bf16.h>

typedef __attribute__((ext_vector_type(8))) __bf16 bf16x8;
typedef __attribute__((ext_vector_type(4))) float f32x4;

// Problem: B=64, L=1024, H=512; M = B*L = 65536, K = 2H = 1024, N = H = 512
// GEMM tiling: BM=128, BN=512 (full N -> A read exactly once), BK=32,
// 512 threads = 8 waves (2M x 4N), per-wave 64x128 output (4x8 fragments).
// LDS rows padded to 40 bf16 (80 B) -> fragment reads ~2-way bank alias (free).
// K tiles: 1024/32 = 32  (R5 bug: had 16 -> OOB B reads -> NaN)

#define KPAD 40
#define NKT 32

// ---------------------------------------------------------------------------
// Pass 0a: q[b,h] = hidden[b,:] @ W_attn[0:512, h] + b_attn[h]   (fp32)
// ---------------------------------------------------------------------------
__global__ void qk(const float* __restrict__ hidden, const float* __restrict__ W_attn,
                   const float* __restrict__ b_attn, float* __restrict__ q) {
    int idx = blockIdx.x * 256 + threadIdx.x;   // < 32768
    int b = idx >> 9;
    int h = idx & 511;
    const float* hv = hidden + b * 512;
    float acc = b_attn[h];
#pragma unroll 8
    for (int k = 0; k < 512; ++k)
        acc = fmaf(hv[k], W_attn[(size_t)k * 512 + h], acc);
    q[idx] = acc;
}

// ---------------------------------------------------------------------------
// Pass 0b: build B tile image: Bimg[kt][n][kk(pad 40)] = bf16(W_attn[512+kt*32+kk][n])
// kt in [0,32). Laid out exactly as the LDS image so global_load_lds streams it.
// ---------------------------------------------------------------------------
__global__ void btk_img(const float* __restrict__ W_attn, __bf16* __restrict__ Bimg) {
    int idx = blockIdx.x * 256 + threadIdx.x;   // < 32*512*40 = 655360
    int kt = idx / (512 * KPAD);
    int r  = idx % (512 * KPAD);
    int n  = r / KPAD;
    int kk = r % KPAD;
    float v = (kk < 32) ? W_attn[(size_t)(512 + kt * 32 + kk) * 512 + n] : 0.f;
    Bimg[idx] = (__bf16)v;
}

// ---------------------------------------------------------------------------
// global -> LDS direct (width 16)
// ---------------------------------------------------------------------------
__device__ inline void gl_lds16(const void* g, void* l) {
    __builtin_amdgcn_global_load_lds(
        (const __attribute__((address_space(1))) void*)g,
        (__attribute__((address_space(3))) void*)l, 16, 0, 0);
}

// ---------------------------------------------------------------------------
// Pass 1: fused GEMM + relu + Wv row-reduce -> logits [65536]
// ---------------------------------------------------------------------------
__global__ __launch_bounds__(512, 2) void gemm_logits2(
    const float* __restrict__ A,       // enc [65536][1024] fp32
    const __bf16* __restrict__ Bimg,   // [32][512][KPAD]
    const float* __restrict__ q,       // [64][512]
    const float* __restrict__ Wv,      // [512]
    float* __restrict__ logits)        // [65536]
{
    __shared__ __bf16 As[2][128 * KPAD];   // 2 x 10 KB
    __shared__ __bf16 Bs[2][512 * KPAD];   // 2 x 40 KB
    __shared__ float red[128][4];

    const int bid = blockIdx.x;
    const int mt = (bid & 7) * 64 + (bid >> 3);   // 0..511, XCD-chunked
    const int t = threadIdx.x;
    const int lane = t & 63;
    const int wid = t >> 6;          // 0..7
    const int wm = wid >> 2;         // 0..1  (M half: 64 rows)
    const int wn = wid & 3;          // 0..3  (N quarter: 128 cols)

    // A staging: thread -> row = t>>2 (0..127), kcol = (t&3)*8 ; 2 x float4
    const int ar = t >> 2;
    const int ak = (t & 3) * 8;
    const float* Ag = A + (size_t)(mt * 128 + ar) * 1024 + ak;
    __bf16* AwrBase0 = &As[0][ar * KPAD + ak];
    __bf16* AwrBase1 = &As[1][ar * KPAD + ak];

    // B staging: 5 global_load_lds per thread; wave-uniform LDS base
    const __bf16* Bg = Bimg + (size_t)(wid * 5) * 512 + lane * 8;

    f32x4 acc[4][8];
#pragma unroll
    for (int m = 0; m < 4; ++m)
#pragma unroll
        for (int n = 0; n < 8; ++n) acc[m][n] = (f32x4)0.0f;

    const int rsel = lane & 15;
    const int kb = (lane >> 4) * 8;

#define STAGE_B(KT, BUF)                                                       \
    {                                                                          \
        const __bf16* src = Bg + (size_t)(KT) * (512 * KPAD);                  \
        _Pragma("unroll") for (int i = 0; i < 5; ++i)                          \
            gl_lds16(src + i * 512, &Bs[BUF][(wid * 5 + i) * 512]);            \
    }

    // ---- prologue: tile 0 into buf 0 ----
    STAGE_B(0, 0)
    float4 p0 = *(const float4*)Ag;
    float4 p1 = *(const float4*)(Ag + 4);
    {
        bf16x8 v;
        v[0] = (__bf16)p0.x; v[1] = (__bf16)p0.y; v[2] = (__bf16)p0.z; v[3] = (__bf16)p0.w;
        v[4] = (__bf16)p1.x; v[5] = (__bf16)p1.y; v[6] = (__bf16)p1.z; v[7] = (__bf16)p1.w;
        *(bf16x8*)AwrBase0 = v;
    }
    __syncthreads();

    for (int kt = 0; kt < NKT; ++kt) {
        const int cur = kt & 1;
        if (kt + 1 < NKT) {
            STAGE_B(kt + 1, cur ^ 1)               // issue early: latency under MFMA
            const float* p = Ag + (kt + 1) * 32;
            p0 = *(const float4*)p;
            p1 = *(const float4*)(p + 4);
        }

        // fragment reads + MFMA on buf[cur]
        bf16x8 af[4];
#pragma unroll
        for (int m = 0; m < 4; ++m)
            af[m] = *(const bf16x8*)&As[cur][(wm * 64 + m * 16 + rsel) * KPAD + kb];
#pragma unroll
        for (int n = 0; n < 8; ++n) {
            bf16x8 bg = *(const bf16x8*)&Bs[cur][(wn * 128 + n * 16 + rsel) * KPAD + kb];
#pragma unroll
            for (int m = 0; m < 4; ++m)
                acc[m][n] = __builtin_amdgcn_mfma_f32_16x16x32_bf16(
                    af[m], bg, acc[m][n], 0, 0, 0);
        }

        if (kt + 1 < NKT) {
            bf16x8 v;
            v[0] = (__bf16)p0.x; v[1] = (__bf16)p0.y; v[2] = (__bf16)p0.z; v[3] = (__bf16)p0.w;
            v[4] = (__bf16)p1.x; v[5] = (__bf16)p1.y; v[6] = (__bf16)p1.z; v[7] = (__bf16)p1.w;
            *(bf16x8*)((cur ^ 1) ? AwrBase1 : AwrBase0) = v;
            __syncthreads();   // drains vmcnt(0) lgkmcnt(0): B lds-loads + A writes
        }
    }
#undef STAGE_B

    // ---- epilogue: logits[row] = sum_{col<512} relu(acc + q[b,col]) * Wv[col]
    const float* qb = q + (mt >> 3) * 512;
    float qv[8], wvv[8];
#pragma unroll
    for (int n = 0; n < 8; ++n) {
        int gc = wn * 128 + n * 16 + rsel;
        qv[n] = qb[gc];
        wvv[n] = Wv[gc];
    }

#pragma unroll
    for (int m = 0; m < 4; ++m) {
#pragma unroll
        for (int j = 0; j < 4; ++j) {
            float s = 0.f;
#pragma unroll
            for (int n = 0; n < 8; ++n) {
                float e = acc[m][n][j] + qv[n];
                s += (e > 0.f ? e : 0.f) * wvv[n];
            }
            s += __shfl_xor(s, 1);
            s += __shfl_xor(s, 2);
            s += __shfl_xor(s, 4);
            s += __shfl_xor(s, 8);
            if (rsel == 0) {
                int r = wm * 64 + m * 16 + (lane >> 4) * 4 + j;
                red[r][wn] = s;
            }
        }
    }
    __syncthreads();
    if (t < 128)
        logits[(size_t)mt * 128 + t] = red[t][0] + red[t][1] + red[t][2] + red[t][3];
}

// ---------------------------------------------------------------------------
// Pass 2: softmax over L=1024 per batch
// ---------------------------------------------------------------------------
__global__ void softmax_k(const float* __restrict__ logits, float* __restrict__ w) {
    __shared__ float smx[4];
    __shared__ float ssum[4];
    int b = blockIdx.x;
    int t = threadIdx.x;
    int lane = t & 63, wid = t >> 6;
    float v[4];
    float mx = -3.0e38f;
#pragma unroll
    for (int i = 0; i < 4; ++i) {
        float s = logits[b * 1024 + t + i * 256];
        v[i] = s;
        mx = fmaxf(mx, s);
    }
#pragma unroll
    for (int off = 32; off >= 1; off >>= 1) mx = fmaxf(mx, __shfl_xor(mx, off));
    if (lane == 0) smx[wid] = mx;
    __syncthreads();
    mx = fmaxf(fmaxf(smx[0], smx[1]), fmaxf(smx[2], smx[3]));
    float e[4];
    float sum = 0.f;
#pragma unroll
    for (int i = 0; i < 4; ++i) { e[i] = __expf(v[i] - mx); sum += e[i]; }
#pragma unroll
    for (int off = 32; off >= 1; off >>= 1) sum += __shfl_xor(sum, off);
    if (lane == 0) ssum[wid] = sum;
    __syncthreads();
    float inv = 1.f / (ssum[0] + ssum[1] + ssum[2] + ssum[3]);
#pragma unroll
    for (int i = 0; i < 4; ++i) w[b * 1024 + t + i * 256] = e[i] * inv;
}

// ---------------------------------------------------------------------------
// Pass 3: partial context: ctxp[lc][b][e] = sum_{l in chunk lc} w[b,l]*enc[b,l,e]
// ---------------------------------------------------------------------------
__global__ void ctx_partial(const float* __restrict__ enc, const float* __restrict__ w,
                            float* __restrict__ ctxp) {
    int blk = blockIdx.x;   // 0..511
    int b = blk >> 3;
    int lc = blk & 7;
    int t = threadIdx.x;    // 256
    __shared__ float wl[128];
    if (t < 128) wl[t] = w[b * 1024 + lc * 128 + t];
    __syncthreads();
    float4 acc = {0.f, 0.f, 0.f, 0.f};
    const float* base = enc + ((size_t)(b * 1024 + lc * 128)) * 1024 + t * 4;
    for (int l = 0; l < 128; ++l) {
        float4 v = *(const float4*)(base + (size_t)l * 1024);
        float s = wl[l];
        acc.x += s * v.x; acc.y += s * v.y; acc.z += s * v.z; acc.w += s * v.w;
    }
    *(float4*)(ctxp + (size_t)(lc * 64 + b) * 1024 + t * 4) = acc;
}

// ---------------------------------------------------------------------------
// Pass 4: out[b][e] = sum_lc ctxp[lc][b][e]
// ---------------------------------------------------------------------------
__global__ void ctx_sum(const float* __restrict__ ctxp, float* __restrict__ out) {
    int idx = blockIdx.x * 256 + threadIdx.x;   // < 16384 (float4 each)
    float4 a = {0.f, 0.f, 0.f, 0.f};
#pragma unroll
    for (int lc = 0; lc < 8; ++lc) {
        float4 v = *(const float4*)(ctxp + (size_t)lc * 65536 + (size_t)idx * 4);
        a.x += v.x; a.y += v.y; a.z += v.z; a.w += v.w;
    }
    *(float4*)(out + (size_t)idx * 4) = a;
}

// ---------------------------------------------------------------------------
extern "C" void kernel_launch(void* const* d_in, const int* in_sizes, int n_in,
                              void* d_out, int out_size, void* d_ws, size_t ws_size,
                              hipStream_t stream) {
    const float* hidden = (const float*)d_in[0];
    const float* enc    = (const float*)d_in[1];
    const float* W_attn = (const float*)d_in[2];
    const float* b_attn = (const float*)d_in[3];
    const float* W_v    = (const float*)d_in[4];
    float* out = (float*)d_out;

    char* ws = (char*)d_ws;
    float*  q      = (float*)(ws + 0);          // 128 KB  [64][512]
    __bf16* Bimg   = (__bf16*)(ws + 131072);    // 1.25 MB [32][512][40]
    float*  logits = (float*)(ws + 1441792);    // 256 KB  [65536]
    float*  wts    = (float*)(ws + 1703936);    // 256 KB  [64][1024]
    float*  ctxp   = (float*)(ws + 1966080);    // 2 MB    [8][64][1024]

    qk<<<128, 256, 0, stream>>>(hidden, W_attn, b_attn, q);
    btk_img<<<2560, 256, 0, stream>>>(W_attn, Bimg);
    gemm_logits2<<<512, 512, 0, stream>>>(enc, Bimg, q, W_v, logits);
    softmax_k<<<64, 256, 0, stream>>>(logits, wts);
    ctx_partial<<<512, 256, 0, stream>>>(enc, wts, ctxp);
    ctx_sum<<<64, 256, 0, stream>>>(ctxp, out);
}

// Round 7
// 188.239 us; speedup vs baseline: 1.0718x; 1.0718x over previous
//
#include <hip/hip_runtime.h>
#include <hip/hip_bf16.h>

typedef __attribute__((ext_vector_type(8))) __bf16 bf16x8;
typedef __attribute__((ext_vector_type(4))) __bf16 bf16x4;
typedef __attribute__((ext_vector_type(4))) float f32x4;

// Problem: B=64, L=1024, H=512; M = B*L = 65536, K = 2H = 1024, N = H = 512
// GEMM: 128x128 tile, BK=32, dbuf LDS, 256 thr (4 waves, 2Mx2N, 64x64/wave).
// KPAD=40 (80 B row stride: 16B-aligned, 2-way bank alias = free).
// LDS = 2*10240 (A) + 2*10240 (B) = 40960 B exactly -> 4 blocks/CU (TLP).

#define KPAD 40
#define NKT 32

// ---------------------------------------------------------------------------
// Pass 0a: q[b,h] = hidden[b,:] @ W_attn[0:512, h] + b_attn[h]   (fp32)
// ---------------------------------------------------------------------------
__global__ void qk(const float* __restrict__ hidden, const float* __restrict__ W_attn,
                   const float* __restrict__ b_attn, float* __restrict__ q) {
    int idx = blockIdx.x * 256 + threadIdx.x;   // < 32768
    int b = idx >> 9;
    int h = idx & 511;
    const float* hv = hidden + b * 512;
    float acc = b_attn[h];
#pragma unroll 8
    for (int k = 0; k < 512; ++k)
        acc = fmaf(hv[k], W_attn[(size_t)k * 512 + h], acc);
    q[idx] = acc;
}

// ---------------------------------------------------------------------------
// Pass 0b: Bt[n][k] = bf16(W_attn[512 + k][n])   -> [512][1024] bf16 (B^T)
// ---------------------------------------------------------------------------
__global__ void btk(const float* __restrict__ W_attn, __bf16* __restrict__ Bt) {
    int idx = blockIdx.x * 256 + threadIdx.x;   // < 524288
    int n = idx >> 10;
    int k = idx & 1023;
    Bt[idx] = (__bf16)W_attn[(size_t)(512 + k) * 512 + n];
}

// ---------------------------------------------------------------------------
// Pass 1: fused GEMM  S = enc @ W2, part = sum_n relu(S+q)*Wv (per 128-col blk)
// ---------------------------------------------------------------------------
__global__ __launch_bounds__(256, 4) void gemm_logits3(
    const float* __restrict__ A, const __bf16* __restrict__ Bt,
    const float* __restrict__ q, const float* __restrict__ Wv,
    float* __restrict__ part)
{
    __shared__ __bf16 As[2][128 * KPAD];   // 2 x 10 KB
    __shared__ __bf16 Bs[2][128 * KPAD];   // 2 x 10 KB
    float* red = (float*)&Bs[0][0];        // overlay: Bs dead after K-loop

    const int bid = blockIdx.x;
    const int swz = (bid & 7) * 256 + (bid >> 3);   // XCD-chunked, bijective
    const int mt = swz >> 2;        // 0..511
    const int nt = swz & 3;         // 0..3

    const int t = threadIdx.x;
    const int lane = t & 63;
    const int wid = t >> 6;
    const int wm = wid >> 1;        // 0..1
    const int wn = wid & 1;         // 0..1

    // A staging: thread -> rows ar+32i (i<4), fp32 cols (t&7)*4 .. +3
    const int ar = t >> 3;
    const int ac = (t & 7) * 4;
    const float* Ag = A + (size_t)(mt * 128 + ar) * 1024 + ac;
    // B staging: thread -> rows br+64i (i<2), bf16 cols (t&3)*8 .. +7
    const int br = t >> 2;
    const int bc = (t & 3) * 8;
    const __bf16* Bg = Bt + (size_t)(nt * 128 + br) * 1024 + bc;

    f32x4 acc[4][4];
#pragma unroll
    for (int m = 0; m < 4; ++m)
#pragma unroll
        for (int n = 0; n < 4; ++n) acc[m][n] = (f32x4)0.0f;

    float4 av[4];
    bf16x8 bv[2];

#define LOADS(K0)                                                              \
    {                                                                          \
        _Pragma("unroll") for (int i = 0; i < 4; ++i)                          \
            av[i] = *(const float4*)(Ag + (size_t)i * 32768 + (K0));           \
        _Pragma("unroll") for (int i = 0; i < 2; ++i)                          \
            bv[i] = *(const bf16x8*)(Bg + (size_t)i * 65536 + (K0));           \
    }

#define WRITES(BUF)                                                            \
    {                                                                          \
        _Pragma("unroll") for (int i = 0; i < 4; ++i) {                        \
            bf16x4 w;                                                          \
            w[0] = (__bf16)av[i].x; w[1] = (__bf16)av[i].y;                    \
            w[2] = (__bf16)av[i].z; w[3] = (__bf16)av[i].w;                    \
            *(bf16x4*)&As[BUF][(ar + i * 32) * KPAD + ac] = w;                 \
        }                                                                      \
        _Pragma("unroll") for (int i = 0; i < 2; ++i)                          \
            *(bf16x8*)&Bs[BUF][(br + i * 64) * KPAD + bc] = bv[i];             \
    }

    // prologue: tile 0 -> buf 0
    LOADS(0)
    WRITES(0)
    __syncthreads();

    const int rsel = lane & 15;
    const int kb = (lane >> 4) * 8;

    for (int kt = 0; kt < NKT; ++kt) {
        const int cur = kt & 1;
        if (kt + 1 < NKT) LOADS((kt + 1) * 32)   // issue early: hide under MFMA

        bf16x8 af[4], bg[4];
#pragma unroll
        for (int m = 0; m < 4; ++m)
            af[m] = *(const bf16x8*)&As[cur][(wm * 64 + m * 16 + rsel) * KPAD + kb];
#pragma unroll
        for (int n = 0; n < 4; ++n)
            bg[n] = *(const bf16x8*)&Bs[cur][(wn * 64 + n * 16 + rsel) * KPAD + kb];
#pragma unroll
        for (int m = 0; m < 4; ++m)
#pragma unroll
            for (int n = 0; n < 4; ++n)
                acc[m][n] = __builtin_amdgcn_mfma_f32_16x16x32_bf16(
                    af[m], bg[n], acc[m][n], 0, 0, 0);

        if (kt + 1 < NKT) {
            WRITES(cur ^ 1)
            __syncthreads();
        }
    }
#undef LOADS
#undef WRITES

    __syncthreads();   // protect Bs (red overlay) from in-flight frag reads

    // Epilogue: part[row] = sum over this block's 128 cols of relu(acc+q)*Wv
    const float* qb = q + (mt >> 3) * 512;
    float qv[4], wvv[4];
#pragma unroll
    for (int n = 0; n < 4; ++n) {
        int gc = nt * 128 + wn * 64 + n * 16 + rsel;
        qv[n] = qb[gc];
        wvv[n] = Wv[gc];
    }

#pragma unroll
    for (int m = 0; m < 4; ++m) {
#pragma unroll
        for (int j = 0; j < 4; ++j) {
            float s = 0.f;
#pragma unroll
            for (int n = 0; n < 4; ++n) {
                float e = acc[m][n][j] + qv[n];
                s += (e > 0.f ? e : 0.f) * wvv[n];
            }
            s += __shfl_xor(s, 1);
            s += __shfl_xor(s, 2);
            s += __shfl_xor(s, 4);
            s += __shfl_xor(s, 8);
            if (rsel == 0) {
                int r = wm * 64 + m * 16 + (lane >> 4) * 4 + j;
                red[r * 2 + wn] = s;
            }
        }
    }
    __syncthreads();
    if (t < 128)
        part[(size_t)nt * 65536 + (size_t)mt * 128 + t] = red[t * 2] + red[t * 2 + 1];
}

// ---------------------------------------------------------------------------
// Pass 2: softmax over L=1024 per batch (sums the 4 col-block partials)
// ---------------------------------------------------------------------------
__global__ void softmax_k(const float* __restrict__ part, float* __restrict__ w) {
    __shared__ float smx[4];
    __shared__ float ssum[4];
    int b = blockIdx.x;
    int t = threadIdx.x;
    int lane = t & 63, wid = t >> 6;
    float v[4];
    float mx = -3.0e38f;
#pragma unroll
    for (int i = 0; i < 4; ++i) {
        int o = b * 1024 + t + i * 256;
        float s = part[o] + part[65536 + o] + part[131072 + o] + part[196608 + o];
        v[i] = s;
        mx = fmaxf(mx, s);
    }
#pragma unroll
    for (int off = 32; off >= 1; off >>= 1) mx = fmaxf(mx, __shfl_xor(mx, off));
    if (lane == 0) smx[wid] = mx;
    __syncthreads();
    mx = fmaxf(fmaxf(smx[0], smx[1]), fmaxf(smx[2], smx[3]));
    float e[4];
    float sum = 0.f;
#pragma unroll
    for (int i = 0; i < 4; ++i) { e[i] = __expf(v[i] - mx); sum += e[i]; }
#pragma unroll
    for (int off = 32; off >= 1; off >>= 1) sum += __shfl_xor(sum, off);
    if (lane == 0) ssum[wid] = sum;
    __syncthreads();
    float inv = 1.f / (ssum[0] + ssum[1] + ssum[2] + ssum[3]);
#pragma unroll
    for (int i = 0; i < 4; ++i) w[b * 1024 + t + i * 256] = e[i] * inv;
}

// ---------------------------------------------------------------------------
// Pass 3: partial context: ctxp[lc][b][e] = sum_{l in chunk lc} w[b,l]*enc[b,l,e]
// ---------------------------------------------------------------------------
__global__ void ctx_partial(const float* __restrict__ enc, const float* __restrict__ w,
                            float* __restrict__ ctxp) {
    int blk = blockIdx.x;   // 0..511
    int b = blk >> 3;
    int lc = blk & 7;
    int t = threadIdx.x;    // 256
    __shared__ float wl[128];
    if (t < 128) wl[t] = w[b * 1024 + lc * 128 + t];
    __syncthreads();
    float4 acc = {0.f, 0.f, 0.f, 0.f};
    const float* base = enc + ((size_t)(b * 1024 + lc * 128)) * 1024 + t * 4;
    for (int l = 0; l < 128; ++l) {
        float4 v = *(const float4*)(base + (size_t)l * 1024);
        float s = wl[l];
        acc.x += s * v.x; acc.y += s * v.y; acc.z += s * v.z; acc.w += s * v.w;
    }
    *(float4*)(ctxp + (size_t)(lc * 64 + b) * 1024 + t * 4) = acc;
}

// ---------------------------------------------------------------------------
// Pass 4: out[b][e] = sum_lc ctxp[lc][b][e]
// ---------------------------------------------------------------------------
__global__ void ctx_sum(const float* __restrict__ ctxp, float* __restrict__ out) {
    int idx = blockIdx.x * 256 + threadIdx.x;   // < 16384 (float4 each)
    float4 a = {0.f, 0.f, 0.f, 0.f};
#pragma unroll
    for (int lc = 0; lc < 8; ++lc) {
        float4 v = *(const float4*)(ctxp + (size_t)lc * 65536 + (size_t)idx * 4);
        a.x += v.x; a.y += v.y; a.z += v.z; a.w += v.w;
    }
    *(float4*)(out + (size_t)idx * 4) = a;
}

// ---------------------------------------------------------------------------
extern "C" void kernel_launch(void* const* d_in, const int* in_sizes, int n_in,
                              void* d_out, int out_size, void* d_ws, size_t ws_size,
                              hipStream_t stream) {
    const float* hidden = (const float*)d_in[0];
    const float* enc    = (const float*)d_in[1];
    const float* W_attn = (const float*)d_in[2];
    const float* b_attn = (const float*)d_in[3];
    const float* W_v    = (const float*)d_in[4];
    float* out = (float*)d_out;

    char* ws = (char*)d_ws;
    float*  q    = (float*)(ws + 0);          // 128 KB  [64][512]
    __bf16* Bt   = (__bf16*)(ws + 131072);    // 1 MB    [512][1024]
    float*  part = (float*)(ws + 1179648);    // 1 MB    [4][65536]
    float*  wts  = (float*)(ws + 2228224);    // 256 KB  [64][1024]
    float*  ctxp = (float*)(ws + 2490368);    // 2 MB    [8][64][1024]

    qk<<<128, 256, 0, stream>>>(hidden, W_attn, b_attn, q);
    btk<<<2048, 256, 0, stream>>>(W_attn, Bt);
    gemm_logits3<<<2048, 256, 0, stream>>>(enc, Bt, q, W_v, part);
    softmax_k<<<64, 256, 0, stream>>>(part, wts);
    ctx_partial<<<512, 256, 0, stream>>>(enc, wts, ctxp);
    ctx_sum<<<64, 256, 0, stream>>>(ctxp, out);
}